// Round 4
// baseline (239.013 us; speedup 1.0000x reference)
//
#include <hip/hip_runtime.h>
#include <math.h>

// Regional Interaction Module — round 7: DRAM-stream-count reduction.
//
// r3/r4/r5/r6 (short blocks, persistent reg-pipeline, plain vs nt stores,
// global_load_lds DMA) ALL tie at ~72 us / 2.3 TB/s. Copy-ubench on this
// machine does 6.3 TB/s through the same L1/MSHR hardware at worse
// latency, so per-CU queue capacity is NOT the cap. The one thing all
// four variants share: ~1000+ resident blocks x 7 plane-strided streams
// = ~8000 concurrent DRAM stream heads (~56/channel, >> ~32 banks per
// pseudo-channel) -> row-buffer thrash -> ~half effective bandwidth.
//
// This round: 256 blocks (1 per CU) x 512 threads, each block walks a
// CONTIGUOUS 8192-group slice (128 KB per plane) over 16 tiles with a
// register double-buffer. Concurrent heads drop to 256 x 7 = 1792
// (~14/channel, within bank capacity), every head densely sequential.
// Per-pixel math identical to r3-r6 (same FMA order, same absmax).

#define HWQ_SHIFT 16             // HW/4 = 65536 float4 groups per plane
#define HWQ (1 << HWQ_SHIFT)

__device__ __forceinline__ float sigm(float x) {
    return __builtin_amdgcn_rcpf(1.0f + __expf(-x));
}

__global__ __launch_bounds__(512, 2) void rim_kernel(
    const float* __restrict__ img,  const float* __restrict__ mask,
    const float* __restrict__ qiw,  const float* __restrict__ qib,
    const float* __restrict__ kiw,  const float* __restrict__ kib,
    const float* __restrict__ viw,  const float* __restrict__ vib,
    const float* __restrict__ qrw,  const float* __restrict__ qrb,
    const float* __restrict__ krw,  const float* __restrict__ krb,
    const float* __restrict__ vrw,  const float* __restrict__ vrb,
    const float* __restrict__ fuw,  const float* __restrict__ fub,
    float* __restrict__ out)
{
    // ---- uniform weight loads (scalar loads -> SGPRs) ----
    const float w_qi0 = qiw[0], w_qi1 = qiw[1], w_qi2 = qiw[2], b_qi = qib[0];
    const float w_ki0 = kiw[0], w_ki1 = kiw[1], w_ki2 = kiw[2], b_ki = kib[0];
    float w_vi[9], b_vi[3];
#pragma unroll
    for (int j = 0; j < 9; ++j) w_vi[j] = viw[j];
#pragma unroll
    for (int j = 0; j < 3; ++j) b_vi[j] = vib[j];
    const float w_qr = qrw[0], b_qr = qrb[0];
    const float w_kr = krw[0], b_kr = krb[0];
    const float w_vr = vrw[0], b_vr = vrb[0];
    float w_fu[18], b_fu[3];
#pragma unroll
    for (int j = 0; j < 18; ++j) w_fu[j] = fuw[j];
#pragma unroll
    for (int j = 0; j < 3; ++j) b_fu[j] = fub[j];

    // 256 blocks: bid -> (batch = bid>>3, slice = bid&7).
    // Block owns groups [slice*8192, slice*8192+8192) of its batch plane,
    // walked as 16 tiles x 512 threads x 1 float4 (densely sequential).
    const int bid   = blockIdx.x;
    const int b     = bid >> 3;                       // batch (block-uniform)
    const int base  = (bid & 7) * 8192 + threadIdx.x; // slice base + lane

    const float4* px = (const float4*)img  + ((size_t)b * 3 << HWQ_SHIFT) + base;
    const float4* pm = (const float4*)mask + ((size_t)b     << HWQ_SHIFT) + base;
    float4*       po = (float4*)out        + ((size_t)b * 3 << HWQ_SHIFT) + base;

    auto compute = [&](const float4& X0q, const float4& X1q, const float4& X2q,
                       const float4& Mq, float4& O0, float4& O1, float4& O2) {
        const float* px0 = &X0q.x; const float* px1 = &X1q.x;
        const float* px2 = &X2q.x; const float* pmq = &Mq.x;
        float* po0 = &O0.x; float* po1 = &O1.x; float* po2 = &O2.x;
#pragma unroll
        for (int l = 0; l < 4; ++l) {
            const float X0 = px0[l], X1 = px1[l], X2 = px2[l], M = pmq[l];

            const float q_i = b_qi + w_qi0 * X0 + w_qi1 * X1 + w_qi2 * X2;
            const float k_i = b_ki + w_ki0 * X0 + w_ki1 * X1 + w_ki2 * X2;
            const float v0  = b_vi[0] + w_vi[0] * X0 + w_vi[1] * X1 + w_vi[2] * X2;
            const float v1  = b_vi[1] + w_vi[3] * X0 + w_vi[4] * X1 + w_vi[5] * X2;
            const float v2  = b_vi[2] + w_vi[6] * X0 + w_vi[7] * X1 + w_vi[8] * X2;
            const float q_r = b_qr + w_qr * M;
            const float k_r = b_kr + w_kr * M;
            const float v_r = b_vr + w_vr * M;

            const float s_ii = sigm(q_i * k_i);
            const float s_ir = sigm(q_i * k_r);
            const float s_rr = sigm(q_r * k_r);
            const float s_ri = sigm(q_r * k_i);

            const float fi0 = s_ii * v0 + s_ir * v_r;
            const float fi1 = s_ii * v1 + s_ir * v_r;
            const float fi2 = s_ii * v2 + s_ir * v_r;
            const float fr0 = s_rr * v_r + s_ri * v0;
            const float fr1 = s_rr * v_r + s_ri * v1;
            const float fr2 = s_rr * v_r + s_ri * v2;

            po0[l] = b_fu[0] + w_fu[0]  * fi0 + w_fu[1]  * fi1 + w_fu[2]  * fi2
                             + w_fu[3]  * fr0 + w_fu[4]  * fr1 + w_fu[5]  * fr2;
            po1[l] = b_fu[1] + w_fu[6]  * fi0 + w_fu[7]  * fi1 + w_fu[8]  * fi2
                             + w_fu[9]  * fr0 + w_fu[10] * fr1 + w_fu[11] * fr2;
            po2[l] = b_fu[2] + w_fu[12] * fi0 + w_fu[13] * fi1 + w_fu[14] * fi2
                             + w_fu[15] * fr0 + w_fu[16] * fr1 + w_fu[17] * fr2;
        }
    };

    // Register double-buffer, fully unrolled 16-tile walk; all indices
    // compile-time (no scratch). Tile t covers groups base + t*512.
    float4 Ax0, Ax1, Ax2, Am;
    float4 Bx0, Bx1, Bx2, Bm;
    float4 o0, o1, o2;

#define LOADS(P, t) \
    P##x0 = px[(t) * 512]; \
    P##x1 = px[(t) * 512 + HWQ]; \
    P##x2 = px[(t) * 512 + 2 * HWQ]; \
    P##m  = pm[(t) * 512];

#define CSTORE(P, t) \
    compute(P##x0, P##x1, P##x2, P##m, o0, o1, o2); \
    po[(t) * 512]           = o0; \
    po[(t) * 512 + HWQ]     = o1; \
    po[(t) * 512 + 2 * HWQ] = o2;

    LOADS(A, 0)
#pragma unroll
    for (int t = 0; t < 16; t += 2) {
        LOADS(B, t + 1)
        CSTORE(A, t)
        if (t + 2 < 16) { LOADS(A, t + 2) }
        CSTORE(B, t + 1)
    }

#undef LOADS
#undef CSTORE
}

extern "C" void kernel_launch(void* const* d_in, const int* in_sizes, int n_in,
                              void* d_out, int out_size, void* d_ws, size_t ws_size,
                              hipStream_t stream) {
    const float* img  = (const float*)d_in[0];
    const float* mask = (const float*)d_in[1];
    const float* qiw  = (const float*)d_in[2];
    const float* qib  = (const float*)d_in[3];
    const float* kiw  = (const float*)d_in[4];
    const float* kib  = (const float*)d_in[5];
    const float* viw  = (const float*)d_in[6];
    const float* vib  = (const float*)d_in[7];
    const float* qrw  = (const float*)d_in[8];
    const float* qrb  = (const float*)d_in[9];
    const float* krw  = (const float*)d_in[10];
    const float* krb  = (const float*)d_in[11];
    const float* vrw  = (const float*)d_in[12];
    const float* vrb  = (const float*)d_in[13];
    const float* fuw  = (const float*)d_in[14];
    const float* fub  = (const float*)d_in[15];
    float* out = (float*)d_out;

    // 256 blocks x 512 threads x 16 tiles x 1 float4 = 2,097,152 groups.
    // 1 block per CU; 7 streams/block -> ~1792 concurrent DRAM streams.
    rim_kernel<<<256, 512, 0, stream>>>(img, mask, qiw, qib, kiw, kib, viw, vib,
                                        qrw, qrb, krw, krb, vrw, vrb, fuw, fub, out);
}

// Round 5
// 231.757 us; speedup vs baseline: 1.0313x; 1.0313x over previous
//
#include <hip/hip_runtime.h>
#include <math.h>

// Regional Interaction Module — round 8: TRUE streaming stores (sc0 sc1 nt).
//
// r3-r7: five orthogonal structures (occupancy 18-58%, reg/LDS/DMA load
// paths, nt vs plain stores, 1792 vs 8000 streams) ALL tie at 72-77 us,
// ~2.3 TB/s HBM. The one untouched invariant: FETCH_SIZE == EXACTLY 50%
// of input bytes in every round. Model: looped bench cycles inputs
// (128 MiB) + write-ALLOCATED output (96 MiB) = 224 MiB through ~256 MiB
// of Infinity Cache -> ~50% steady-state read hit rate, structurally
// invariant. __builtin_nontemporal_store didn't move FETCH because nt
// alone doesn't bypass MALL on gfx950; write-around needs the full
// sc0 sc1 nt cache-policy combo (gfx94x CPol). This round: identical to
// r5 except the 6 output stores are inline-asm
//   global_store_dwordx4 ... sc0 sc1 nt
// Cycling footprint -> 128 MiB < LLC -> inputs stay resident -> FETCH
// collapses -> HBM bytes 168 -> ~100-130 MiB. Byte-count attack: works
// even if the ~2.3 TB/s rate wall stands.

#define HW_SHIFT  18             // HW = 512*512 = 1<<18 floats per plane
#define HWQ_SHIFT 16             // HW/4 float4 groups per plane
#define HWQ (1 << HWQ_SHIFT)

typedef float vfloat4 __attribute__((ext_vector_type(4)));

__device__ __forceinline__ float sigm(float x) {
    return __builtin_amdgcn_rcpf(1.0f + __expf(-x));
}

// Streaming store: no-allocate at L2 and MALL (sc0 sc1 nt), still fully
// visible to post-kernel readers (writes drain toward memory).
__device__ __forceinline__ void stream_store4(const float4& v, float4* p) {
    vfloat4 w = {v.x, v.y, v.z, v.w};
    asm volatile("global_store_dwordx4 %0, %1, off sc0 sc1 nt"
                 :: "v"(p), "v"(w) : "memory");
}

__global__ __launch_bounds__(256) void rim_kernel(
    const float* __restrict__ img,  const float* __restrict__ mask,
    const float* __restrict__ qiw,  const float* __restrict__ qib,
    const float* __restrict__ kiw,  const float* __restrict__ kib,
    const float* __restrict__ viw,  const float* __restrict__ vib,
    const float* __restrict__ qrw,  const float* __restrict__ qrb,
    const float* __restrict__ krw,  const float* __restrict__ krb,
    const float* __restrict__ vrw,  const float* __restrict__ vrb,
    const float* __restrict__ fuw,  const float* __restrict__ fub,
    float* __restrict__ out)
{
    // ---- uniform weight loads (scalar loads -> SGPRs) ----
    const float w_qi0 = qiw[0], w_qi1 = qiw[1], w_qi2 = qiw[2], b_qi = qib[0];
    const float w_ki0 = kiw[0], w_ki1 = kiw[1], w_ki2 = kiw[2], b_ki = kib[0];
    float w_vi[9], b_vi[3];
#pragma unroll
    for (int j = 0; j < 9; ++j) w_vi[j] = viw[j];
#pragma unroll
    for (int j = 0; j < 3; ++j) b_vi[j] = vib[j];
    const float w_qr = qrw[0], b_qr = qrb[0];
    const float w_kr = krw[0], b_kr = krb[0];
    const float w_vr = vrw[0], b_vr = vrb[0];
    float w_fu[18], b_fu[3];
#pragma unroll
    for (int j = 0; j < 18; ++j) w_fu[j] = fuw[j];
#pragma unroll
    for (int j = 0; j < 3; ++j) b_fu[j] = fub[j];

    // Block covers 512 consecutive float4 groups; 512 | 65536 so the whole
    // block (both halves) lives in one batch plane.
    const int g0  = blockIdx.x * 512 + threadIdx.x;   // first group
    const int b   = g0 >> HWQ_SHIFT;                  // batch (wave-uniform)
    const int hw0 = g0 & (HWQ - 1);
    const int hw1 = hw0 + 256;

    const float4* ip = (const float4*)(img  + ((size_t)b * 3 << HW_SHIFT));
    const float4* mp = (const float4*)(mask + ((size_t)b     << HW_SHIFT));

    // ---- all 8 loads upfront: 128B per thread in flight ----
    float4 xa0 = ip[hw0];
    float4 xa1 = ip[hw0 + HWQ];
    float4 xa2 = ip[hw0 + 2 * HWQ];
    float4 mqa = mp[hw0];
    float4 xb0 = ip[hw1];
    float4 xb1 = ip[hw1 + HWQ];
    float4 xb2 = ip[hw1 + 2 * HWQ];
    float4 mqb = mp[hw1];

    auto compute = [&](const float4& X0q, const float4& X1q, const float4& X2q,
                       const float4& Mq, float4& O0, float4& O1, float4& O2) {
        const float* px0 = &X0q.x; const float* px1 = &X1q.x;
        const float* px2 = &X2q.x; const float* pm  = &Mq.x;
        float* po0 = &O0.x; float* po1 = &O1.x; float* po2 = &O2.x;
#pragma unroll
        for (int l = 0; l < 4; ++l) {
            const float X0 = px0[l], X1 = px1[l], X2 = px2[l], M = pm[l];

            const float q_i = b_qi + w_qi0 * X0 + w_qi1 * X1 + w_qi2 * X2;
            const float k_i = b_ki + w_ki0 * X0 + w_ki1 * X1 + w_ki2 * X2;
            const float v0  = b_vi[0] + w_vi[0] * X0 + w_vi[1] * X1 + w_vi[2] * X2;
            const float v1  = b_vi[1] + w_vi[3] * X0 + w_vi[4] * X1 + w_vi[5] * X2;
            const float v2  = b_vi[2] + w_vi[6] * X0 + w_vi[7] * X1 + w_vi[8] * X2;
            const float q_r = b_qr + w_qr * M;
            const float k_r = b_kr + w_kr * M;
            const float v_r = b_vr + w_vr * M;

            const float s_ii = sigm(q_i * k_i);
            const float s_ir = sigm(q_i * k_r);
            const float s_rr = sigm(q_r * k_r);
            const float s_ri = sigm(q_r * k_i);

            const float fi0 = s_ii * v0 + s_ir * v_r;
            const float fi1 = s_ii * v1 + s_ir * v_r;
            const float fi2 = s_ii * v2 + s_ir * v_r;
            const float fr0 = s_rr * v_r + s_ri * v0;
            const float fr1 = s_rr * v_r + s_ri * v1;
            const float fr2 = s_rr * v_r + s_ri * v2;

            po0[l] = b_fu[0] + w_fu[0]  * fi0 + w_fu[1]  * fi1 + w_fu[2]  * fi2
                             + w_fu[3]  * fr0 + w_fu[4]  * fr1 + w_fu[5]  * fr2;
            po1[l] = b_fu[1] + w_fu[6]  * fi0 + w_fu[7]  * fi1 + w_fu[8]  * fi2
                             + w_fu[9]  * fr0 + w_fu[10] * fr1 + w_fu[11] * fr2;
            po2[l] = b_fu[2] + w_fu[12] * fi0 + w_fu[13] * fi1 + w_fu[14] * fi2
                             + w_fu[15] * fr0 + w_fu[16] * fr1 + w_fu[17] * fr2;
        }
    };

    float4* op = (float4*)(out + ((size_t)b * 3 << HW_SHIFT));

    float4 o0, o1, o2;
    compute(xa0, xa1, xa2, mqa, o0, o1, o2);
    stream_store4(o0, op + hw0);
    stream_store4(o1, op + hw0 + HWQ);
    stream_store4(o2, op + hw0 + 2 * HWQ);

    compute(xb0, xb1, xb2, mqb, o0, o1, o2);
    stream_store4(o0, op + hw1);
    stream_store4(o1, op + hw1 + HWQ);
    stream_store4(o2, op + hw1 + 2 * HWQ);
}

extern "C" void kernel_launch(void* const* d_in, const int* in_sizes, int n_in,
                              void* d_out, int out_size, void* d_ws, size_t ws_size,
                              hipStream_t stream) {
    const float* img  = (const float*)d_in[0];
    const float* mask = (const float*)d_in[1];
    const float* qiw  = (const float*)d_in[2];
    const float* qib  = (const float*)d_in[3];
    const float* kiw  = (const float*)d_in[4];
    const float* kib  = (const float*)d_in[5];
    const float* viw  = (const float*)d_in[6];
    const float* vib  = (const float*)d_in[7];
    const float* qrw  = (const float*)d_in[8];
    const float* qrb  = (const float*)d_in[9];
    const float* krw  = (const float*)d_in[10];
    const float* krb  = (const float*)d_in[11];
    const float* vrw  = (const float*)d_in[12];
    const float* vrb  = (const float*)d_in[13];
    const float* fuw  = (const float*)d_in[14];
    const float* fub  = (const float*)d_in[15];
    float* out = (float*)d_out;

    // n4 = 32*65536 = 2,097,152 float4 groups; 2 per thread ->
    // 1,048,576 threads = 4096 blocks x 256 (exact fit, no bounds check).
    rim_kernel<<<4096, 256, 0, stream>>>(img, mask, qiw, qib, kiw, kib, viw, vib,
                                         qrw, qrb, krw, krb, vrw, vrb, fuw, fub, out);
}